// Round 1
// baseline (308.057 us; speedup 1.0000x reference)
//
#include <hip/hip_runtime.h>

#define NUM_ROWS 16384
#define NF 64
#define LANES_PER_ROW 16   // each lane loads float4 -> 16*4 = 64 factors

__global__ __launch_bounds__(256) void MatrixFactorization_18425409700541_kernel(
    const int*   __restrict__ users,
    const int*   __restrict__ items,
    const float* __restrict__ bias_user,
    const float* __restrict__ bias_item,
    const float* __restrict__ o_avg,
    const float* __restrict__ user_table,
    const float* __restrict__ item_table,
    float*       __restrict__ out)
{
    const int tid  = blockIdx.x * blockDim.x + threadIdx.x;
    const int row  = tid >> 4;        // 16 lanes per row
    const int lane = tid & 15;
    if (row >= NUM_ROWS) return;

    const int uidx = users[row];      // broadcast load across the 16 lanes
    const int iidx = items[row];

    const float4 u = *(const float4*)(user_table + (size_t)uidx * NF + lane * 4);
    const float4 v = *(const float4*)(item_table + (size_t)iidx * NF + lane * 4);

    float s = u.x * v.x + u.y * v.y + u.z * v.z + u.w * v.w;

    // Reduce across the 16 lanes of this row (segments aligned to 16 lanes).
    s += __shfl_down(s, 8, LANES_PER_ROW);
    s += __shfl_down(s, 4, LANES_PER_ROW);
    s += __shfl_down(s, 2, LANES_PER_ROW);
    s += __shfl_down(s, 1, LANES_PER_ROW);

    if (lane == 0) {
        out[row] = s + bias_user[row] + bias_item[row] + o_avg[0];
    }
}

extern "C" void kernel_launch(void* const* d_in, const int* in_sizes, int n_in,
                              void* d_out, int out_size, void* d_ws, size_t ws_size,
                              hipStream_t stream) {
    // setup_inputs order:
    // 0 users (B,1) int, 1 items (B,1) int, 2 bias_user (B,) f32,
    // 3 bias_item (B,) f32, 4 o_avg (1,) f32, 5 c_score (1,) f32 (unused),
    // 6 user_table (1M,64) f32, 7 item_table (100K,64) f32
    const int*   users      = (const int*)d_in[0];
    const int*   items      = (const int*)d_in[1];
    const float* bias_user  = (const float*)d_in[2];
    const float* bias_item  = (const float*)d_in[3];
    const float* o_avg      = (const float*)d_in[4];
    const float* user_table = (const float*)d_in[6];
    const float* item_table = (const float*)d_in[7];
    float*       out        = (float*)d_out;

    const int threads = 256;
    const int total   = NUM_ROWS * LANES_PER_ROW;           // 262144
    const int blocks  = (total + threads - 1) / threads;    // 1024

    MatrixFactorization_18425409700541_kernel<<<blocks, threads, 0, stream>>>(
        users, items, bias_user, bias_item, o_avg, user_table, item_table, out);
}

// Round 2
// 304.823 us; speedup vs baseline: 1.0106x; 1.0106x over previous
//
#include <hip/hip_runtime.h>

#define NUM_ROWS 16384
#define NF 64
#define LANES_PER_ROW 16   // each lane loads float4 -> 16*4 = 64 factors

__global__ __launch_bounds__(256) void MatrixFactorization_18425409700541_kernel(
    const int*   __restrict__ users,
    const int*   __restrict__ items,
    const float* __restrict__ bias_user,
    const float* __restrict__ bias_item,
    const float* __restrict__ o_avg,
    const float* __restrict__ user_table,
    const float* __restrict__ item_table,
    float*       __restrict__ out)
{
    const int tid  = blockIdx.x * blockDim.x + threadIdx.x;
    const int row  = tid >> 4;        // 16 lanes per row
    const int lane = tid & 15;
    if (row >= NUM_ROWS) return;

    // Issue all independent loads up front so their latencies overlap.
    const int   uidx = users[row];    // broadcast within the 16-lane segment
    const int   iidx = items[row];
    const float bu   = bias_user[row];   // 4 distinct addrs/wave, 1 cache line
    const float bi   = bias_item[row];
    const float oa   = o_avg[0];

    const float4 u = *(const float4*)(user_table + (size_t)uidx * NF + lane * 4);
    const float4 v = *(const float4*)(item_table + (size_t)iidx * NF + lane * 4);

    float s = u.x * v.x + u.y * v.y + u.z * v.z + u.w * v.w;

    // Reduce across the 16 lanes of this row (segments aligned to 16 lanes).
    s += __shfl_down(s, 8, LANES_PER_ROW);
    s += __shfl_down(s, 4, LANES_PER_ROW);
    s += __shfl_down(s, 2, LANES_PER_ROW);
    s += __shfl_down(s, 1, LANES_PER_ROW);

    if (lane == 0) {
        out[row] = s + bu + bi + oa;   // bias math pre-overlapped with shuffles
    }
}

extern "C" void kernel_launch(void* const* d_in, const int* in_sizes, int n_in,
                              void* d_out, int out_size, void* d_ws, size_t ws_size,
                              hipStream_t stream) {
    // setup_inputs order:
    // 0 users (B,1) int, 1 items (B,1) int, 2 bias_user (B,) f32,
    // 3 bias_item (B,) f32, 4 o_avg (1,) f32, 5 c_score (1,) f32 (unused),
    // 6 user_table (1M,64) f32, 7 item_table (100K,64) f32
    const int*   users      = (const int*)d_in[0];
    const int*   items      = (const int*)d_in[1];
    const float* bias_user  = (const float*)d_in[2];
    const float* bias_item  = (const float*)d_in[3];
    const float* o_avg      = (const float*)d_in[4];
    const float* user_table = (const float*)d_in[6];
    const float* item_table = (const float*)d_in[7];
    float*       out        = (float*)d_out;

    const int threads = 256;
    const int total   = NUM_ROWS * LANES_PER_ROW;           // 262144
    const int blocks  = (total + threads - 1) / threads;    // 1024

    MatrixFactorization_18425409700541_kernel<<<blocks, threads, 0, stream>>>(
        users, items, bias_user, bias_item, o_avg, user_table, item_table, out);
}